// Round 3
// baseline (666.840 us; speedup 1.0000x reference)
//
#include <hip/hip_runtime.h>
#include <stdint.h>
#include <stddef.h>

#define B_N   2048
#define T_SEQ 200
#define H_DIM 128

typedef __attribute__((ext_vector_type(8))) short short8;
typedef __attribute__((ext_vector_type(4))) float floatx4;

// ws layout (bytes) — total 1,411,072 <= 1,638,400 proven safe in R1
#define OFF_ATT 0u         // ushort[B][T]        819200
#define OFF_C   819200u    // float [B][64]       524288
#define OFF_U1  1343488u   // float [128][64]      32768
#define OFF_FR  1376256u   // short8[4][8][64]     32768
#define OFF_W1F 1409024u   // short8[2][64]         2048

__device__ __forceinline__ unsigned rnd_bf(float f) {
  union { float f; unsigned u; } v; v.f = f;
  return v.u + 0x7FFFu + ((v.u >> 16) & 1u);
}
__device__ __forceinline__ unsigned short f2bf(float f) {
  return (unsigned short)(rnd_bf(f) >> 16);
}
__device__ __forceinline__ unsigned pack2bf(float lo, float hi) {
  return __builtin_amdgcn_perm(rnd_bf(hi), rnd_bf(lo), 0x07060302u);
}
__device__ __forceinline__ float bf2f(unsigned short u) {
  union { unsigned u; float f; } v; v.u = ((unsigned)u) << 16; return v.f;
}

#define LOG2E 1.4426950408889634f
__device__ __forceinline__ float fsig(float x) {
  return 1.0f / (1.0f + __builtin_amdgcn_exp2f(-LOG2E * x));
}
__device__ __forceinline__ float ftanh(float x) {
  return fmaf(2.0f, 1.0f / (1.0f + __builtin_amdgcn_exp2f(-2.0f * LOG2E * x)), -1.0f);
}

__device__ __forceinline__ floatx4 mfma16(short8 a, short8 b, floatx4 c) {
  return __builtin_amdgcn_mfma_f32_16x16x32_bf16(a, b, c, 0, 0, 0);
}
__device__ __forceinline__ short8 pack8(const float* p) {
  short8 r;
#pragma unroll
  for (int j = 0; j < 8; ++j) r[j] = (short)f2bf(p[j]);
  return r;
}

// wave-local LDS fence: writes by this wave visible to its own later reads
#define WAVE_LDS_FENCE() __asm__ volatile("s_waitcnt lgkmcnt(0)" ::: "memory")

// ---------------------------------------------------------------------------
// prep: fold W0 into u1 (fp32) + bf16 MFMA B-fragments for layer0/layer1.
// ---------------------------------------------------------------------------
__global__ __launch_bounds__(256) void prep_kernel(
    const float* __restrict__ W0, const float* __restrict__ W1,
    float* __restrict__ u1_ws, short8* __restrict__ fr_ws,
    short8* __restrict__ w1f_ws)
{
  const int tid = threadIdx.x;
  for (int i = tid; i < 128 * 64; i += 256) {
    int k = i >> 6, o = i & 63;
    u1_ws[i] = W0[o * 512 + k] + W0[o * 512 + 256 + k];
  }
  for (int f = tid; f < 4 * 8 * 64; f += 256) {
    int ln = f & 63, kc = (f >> 6) & 7, tt = f >> 9;
    int o = tt * 16 + (ln & 15);
    int k0 = kc * 32 + ((ln >> 4) * 8);
    short8 v;
#pragma unroll
    for (int j = 0; j < 8; ++j) {
      int ks = k0 + j;
      float x = (ks < 128) ? (W0[o * 512 + 128 + ks] - W0[o * 512 + 256 + ks])
                           : W0[o * 512 + 384 + (ks - 128)];
      v[j] = (short)f2bf(x);
    }
    fr_ws[f] = v;
  }
  for (int f = tid; f < 2 * 64; f += 256) {
    int ln = f & 63, kc = f >> 6;
    int n = ln & 15, k0 = kc * 32 + ((ln >> 4) * 8);
    short8 v;
#pragma unroll
    for (int j = 0; j < 8; ++j) v[j] = (short)f2bf(W1[n * 64 + k0 + j]);
    w1f_ws[f] = v;
  }
}

// ---------------------------------------------------------------------------
// c_kernel: c[b][o] = b0[o] + sum_k q[b][k] * u1[k][o].  16 b per block.
// ---------------------------------------------------------------------------
__global__ __launch_bounds__(256) void c_kernel(
    const float* __restrict__ query, const float* __restrict__ u1_ws,
    const float* __restrict__ b0, float* __restrict__ c_ws)
{
  const int blk = blockIdx.x, tid = threadIdx.x;
  __shared__ float qs[16 * 128];
  for (int i = tid; i < 512; i += 256)
    *(float4*)&qs[i * 4] = *(const float4*)(query + (size_t)blk * 2048 + i * 4);
  __syncthreads();
  const int o = tid & 63, bb = tid >> 6;
  float a0 = b0[o], a1 = a0, a2 = a0, a3 = a0;
  const float* qr = qs + bb * 512;
#pragma unroll 4
  for (int k = 0; k < 128; ++k) {
    float w = u1_ws[k * 64 + o];
    a0 = fmaf(qr[k], w, a0);
    a1 = fmaf(qr[128 + k], w, a1);
    a2 = fmaf(qr[256 + k], w, a2);
    a3 = fmaf(qr[384 + k], w, a3);
  }
  const int b = blk * 16 + bb * 4;
  c_ws[(b + 0) * 64 + o] = a0;
  c_ws[(b + 1) * 64 + o] = a1;
  c_ws[(b + 2) * 64 + o] = a2;
  c_ws[(b + 3) * 64 + o] = a3;
}

// ---------------------------------------------------------------------------
// att v3: zero block barriers. Each wave owns 16 t-rows end-to-end:
// stage own A rows -> layer0 MFMA (frags from L2-hot ws) -> wave-local
// transpose through own A rows -> layer1 MFMA -> shfl-reduce layer2.
// ---------------------------------------------------------------------------
__global__ __launch_bounds__(256) void att_kernel(
    const float* __restrict__ query, const float* __restrict__ keys,
    const float* __restrict__ c_ws, const short8* __restrict__ fr_ws,
    const short8* __restrict__ w1f_ws, const float* __restrict__ b1,
    const float* __restrict__ Wd, const float* __restrict__ bd,
    const int* __restrict__ klen, unsigned short* __restrict__ attb)
{
  const int b   = blockIdx.y;
  const int tt0 = blockIdx.x * 64;
  const int tid = threadIdx.x;
  const int lane = tid & 63, wv = tid >> 6;
  const int l15 = lane & 15;
  const int kb = (lane >> 4) * 8;

  __shared__ unsigned short A[64][264];   // [t][k] bf16, K=256; wave-partitioned rows

  const int len = klen[b];
  if (tt0 >= len) {
    if (tid < 64) {
      int tg = tt0 + tid;
      if (tg < T_SEQ) attb[(size_t)b * T_SEQ + tg] = 0;
    }
    return;
  }

  {  // stage A = [k | q*k] bf16 — wave-local rows wv*16..wv*16+15
    int tl = wv * 16 + (lane >> 2), q4 = lane & 3;
    int tg = tt0 + tl;
    bool v = (tg < T_SEQ);
    const float* krow = keys + ((size_t)b * T_SEQ + (v ? tg : 0)) * H_DIM + q4 * 32;
    const float* qrow = query + (size_t)b * H_DIM + q4 * 32;
#pragma unroll
    for (int i = 0; i < 32; i += 4) {
      float4 kv = v ? *(const float4*)(krow + i) : make_float4(0.f, 0.f, 0.f, 0.f);
      float4 qv = *(const float4*)(qrow + i);
      int col = q4 * 32 + i;
      *(unsigned*)&A[tl][col]           = pack2bf(kv.x, kv.y);
      *(unsigned*)&A[tl][col + 2]       = pack2bf(kv.z, kv.w);
      *(unsigned*)&A[tl][128 + col]     = pack2bf(kv.x * qv.x, kv.y * qv.y);
      *(unsigned*)&A[tl][128 + col + 2] = pack2bf(kv.z * qv.z, kv.w * qv.w);
    }
  }
  WAVE_LDS_FENCE();

  // A-fragments for this wave's 16 t-rows (K=256)
  short8 af[8];
  {
    int arow = wv * 16 + l15;
#pragma unroll
    for (int kc = 0; kc < 8; ++kc) af[kc] = *(const short8*)&A[arow][kc * 32 + kb];
  }

  // layer0: 4 o-tiles, B-frags streamed from ws (L2-hot, same for all blocks)
  float a0v[4][4];
#pragma unroll
  for (int tt = 0; tt < 4; ++tt) {
    float co = c_ws[(size_t)b * 64 + tt * 16 + l15];
    floatx4 acc = {co, co, co, co};
    const short8* frp = fr_ws + (size_t)tt * 512 + lane;
#pragma unroll
    for (int kc = 0; kc < 8; ++kc) acc = mfma16(af[kc], frp[kc * 64], acc);
#pragma unroll
    for (int r = 0; r < 4; ++r) a0v[tt][r] = fsig(acc[r]);
  }

  // wave-local transpose: write a0 (D-layout) back into own A rows
  {
    int wrow = wv * 16 + (lane >> 4) * 4;
#pragma unroll
    for (int tt = 0; tt < 4; ++tt)
#pragma unroll
      for (int r = 0; r < 4; ++r)
        A[wrow + r][tt * 16 + l15] = f2bf(a0v[tt][r]);
  }
  WAVE_LDS_FENCE();

  // layer1: 16 t-rows x 16 outputs, K=64
  float b1v = b1[l15];
  floatx4 acc1 = {b1v, b1v, b1v, b1v};
  {
    int arow = wv * 16 + l15;
    acc1 = mfma16(*(const short8*)&A[arow][kb],      w1f_ws[lane],      acc1);
    acc1 = mfma16(*(const short8*)&A[arow][32 + kb], w1f_ws[64 + lane], acc1);
  }

  // layer2: v = sigmoid(acc1)*Wd, reduce across the 16-lane col group
  {
    float wd = Wd[l15];
    float v0 = fsig(acc1[0]) * wd, v1 = fsig(acc1[1]) * wd;
    float v2 = fsig(acc1[2]) * wd, v3 = fsig(acc1[3]) * wd;
#pragma unroll
    for (int m = 1; m < 16; m <<= 1) {
      v0 += __shfl_xor(v0, m, 64);
      v1 += __shfl_xor(v1, m, 64);
      v2 += __shfl_xor(v2, m, 64);
      v3 += __shfl_xor(v3, m, 64);
    }
    if (l15 == 0) {
      float bdv = bd[0];
      int tbase = tt0 + wv * 16 + (lane >> 4) * 4;
      float vv[4] = {v0, v1, v2, v3};
#pragma unroll
      for (int r = 0; r < 4; ++r) {
        int tg = tbase + r;
        if (tg < T_SEQ)
          attb[(size_t)b * T_SEQ + tg] = (tg < len) ? f2bf(vv[r] + bdv) : (unsigned short)0;
      }
    }
  }
}

// ---------------------------------------------------------------------------
// AUGRU scan v3: 256 blocks x 8 rows x 512 thr (all CUs). A-frag row=lane&7
// (broadcast duplicate rows 8-15 -> conflict-free 8x4-bank tiling). One
// lgkm-only barrier per step; k prefetched two steps ahead (vmcnt in flight).
// ---------------------------------------------------------------------------
__global__ __launch_bounds__(512, 2) void scan_kernel(
    const float* __restrict__ keys, const float* __restrict__ Wih,
    const float* __restrict__ Whh, const float* __restrict__ bih,
    const float* __restrict__ bhh, const int* __restrict__ klen,
    const unsigned short* __restrict__ attb, float* __restrict__ out)
{
  const int r0 = blockIdx.x * 8;
  const int tid = threadIdx.x;
  const int lane = tid & 63, wv = tid >> 6;

  __shared__ unsigned short hbf[2][8][136];
  __shared__ unsigned short kbf[2][8][136];
  __shared__ float att_s[T_SEQ][8];
  __shared__ int len_s[8];

  if (tid < 8) len_s[tid] = klen[r0 + tid];
  for (int i = tid; i < 8 * 136; i += 512) ((unsigned short*)hbf[0])[i] = 0;
  for (int i = tid; i < T_SEQ * 8; i += 512) {
    int t = i >> 3, m = i & 7;
    att_s[t][m] = bf2f(attb[(size_t)(r0 + m) * T_SEQ + t]);
  }
  const bool stager = (tid < 256);
  const int pm = (tid >> 5) & 7, pj = (tid & 31) * 4;
  const float* kbase = keys + ((size_t)(r0 + pm) * T_SEQ) * H_DIM + pj;
  float4 kv_next;
  if (stager) {
    float4 kv = *(const float4*)kbase;          // k_0
    uint2 p; p.x = pack2bf(kv.x, kv.y); p.y = pack2bf(kv.z, kv.w);
    *(uint2*)&kbf[0][pm][pj] = p;
    kv_next = *(const float4*)(kbase + H_DIM);  // k_1
  }

  // weight B-fragments in registers (same layout as R2)
  short8 whf[3][4], wif[3][4];
  const int ocol = wv * 16 + (lane & 15);
  const int kb = (lane >> 4) * 8;
#pragma unroll
  for (int g = 0; g < 3; ++g) {
    int row = g * 128 + ocol;
#pragma unroll
    for (int kc = 0; kc < 4; ++kc) {
      int kk = kc * 32 + kb;
      whf[g][kc] = pack8(Whh + (size_t)row * H_DIM + kk);
      wif[g][kc] = pack8(Wih + (size_t)row * H_DIM + kk);
    }
  }
  const float br_  = bih[ocol] + bhh[ocol];
  const float bz_  = bih[128 + ocol] + bhh[128 + ocol];
  const float bin_ = bih[256 + ocol];
  const float bhn_ = bhh[256 + ocol];

  __syncthreads();

  int tmax = 0;
#pragma unroll
  for (int m = 0; m < 8; ++m) tmax = max(tmax, len_s[m]);
  const int mrow0 = (lane >> 4) * 4;       // quads 0,1 valid (rows 0-7)
  const bool valid_q = (mrow0 < 8);
  int lenr[4];
  float hreg[4];
#pragma unroll
  for (int r = 0; r < 4; ++r) { lenr[r] = len_s[(mrow0 + r) & 7]; hreg[r] = 0.0f; }
  const int arow = lane & 7;               // duplicate rows -> LDS broadcast

  for (int t = 0; t < tmax; ++t) {
    const int buf = t & 1, nbuf = buf ^ 1;
    float4 kv_fut;
    if (stager) {
      int tf = min(t + 2, T_SEQ - 1);
      kv_fut = *(const float4*)(kbase + (size_t)tf * H_DIM);
    }

    short8 ah0 = *(const short8*)&hbf[buf][arow][kb];
    short8 ah1 = *(const short8*)&hbf[buf][arow][32 + kb];
    short8 ah2 = *(const short8*)&hbf[buf][arow][64 + kb];
    short8 ah3 = *(const short8*)&hbf[buf][arow][96 + kb];
    short8 ak0 = *(const short8*)&kbf[buf][arow][kb];
    short8 ak1 = *(const short8*)&kbf[buf][arow][32 + kb];
    short8 ak2 = *(const short8*)&kbf[buf][arow][64 + kb];
    short8 ak3 = *(const short8*)&kbf[buf][arow][96 + kb];

    floatx4 acc_r = {br_, br_, br_, br_};
    floatx4 acc_z = {bz_, bz_, bz_, bz_};
    floatx4 ahn   = {bhn_, bhn_, bhn_, bhn_};
    floatx4 ain   = {bin_, bin_, bin_, bin_};

    acc_r = mfma16(ah0, whf[0][0], acc_r); acc_r = mfma16(ak0, wif[0][0], acc_r);
    acc_z = mfma16(ah0, whf[1][0], acc_z); acc_z = mfma16(ak0, wif[1][0], acc_z);
    ahn   = mfma16(ah0, whf[2][0], ahn);   ain   = mfma16(ak0, wif[2][0], ain);
    acc_r = mfma16(ah1, whf[0][1], acc_r); acc_r = mfma16(ak1, wif[0][1], acc_r);
    acc_z = mfma16(ah1, whf[1][1], acc_z); acc_z = mfma16(ak1, wif[1][1], acc_z);
    ahn   = mfma16(ah1, whf[2][1], ahn);   ain   = mfma16(ak1, wif[2][1], ain);
    acc_r = mfma16(ah2, whf[0][2], acc_r); acc_r = mfma16(ak2, wif[0][2], acc_r);
    acc_z = mfma16(ah2, whf[1][2], acc_z); acc_z = mfma16(ak2, wif[1][2], acc_z);
    ahn   = mfma16(ah2, whf[2][2], ahn);   ain   = mfma16(ak2, wif[2][2], ain);
    acc_r = mfma16(ah3, whf[0][3], acc_r); acc_r = mfma16(ak3, wif[0][3], acc_r);
    acc_z = mfma16(ah3, whf[1][3], acc_z); acc_z = mfma16(ak3, wif[1][3], acc_z);
    ahn   = mfma16(ah3, whf[2][3], ahn);   ain   = mfma16(ak3, wif[2][3], ain);

#pragma unroll
    for (int r = 0; r < 4; ++r) {
      float at = att_s[t][(mrow0 + r) & 7];
      float rr = fsig(acc_r[r]);
      float zz = fsig(acc_z[r]);
      float nn = ftanh(ain[r] + rr * ahn[r]);
      float z2 = at * zz;
      float hn = fmaf(z2, nn - hreg[r], hreg[r]);
      hreg[r] = (t < lenr[r]) ? hn : hreg[r];
      if (valid_q) hbf[nbuf][(mrow0 + r) & 7][ocol] = f2bf(hreg[r]);
    }
    if (stager) {
      uint2 p; p.x = pack2bf(kv_next.x, kv_next.y); p.y = pack2bf(kv_next.z, kv_next.w);
      *(uint2*)&kbf[nbuf][pm][pj] = p;
      kv_next = kv_fut;
    }
    // lgkm-only barrier: k prefetch (vmcnt) stays in flight across it
    __asm__ volatile("s_waitcnt lgkmcnt(0)\n\ts_barrier" ::: "memory");
  }

  if (valid_q) {
#pragma unroll
    for (int r = 0; r < 4; ++r)
      out[(size_t)(r0 + mrow0 + r) * H_DIM + ocol] = hreg[r];
  }
}

extern "C" void kernel_launch(void* const* d_in, const int* in_sizes, int n_in,
                              void* d_out, int out_size, void* d_ws, size_t ws_size,
                              hipStream_t stream) {
  const float* query = (const float*)d_in[0];
  const float* keys  = (const float*)d_in[1];
  const float* W0    = (const float*)d_in[2];
  const float* b0    = (const float*)d_in[3];
  const float* W1    = (const float*)d_in[4];
  const float* b1    = (const float*)d_in[5];
  const float* Wd    = (const float*)d_in[6];
  const float* bd    = (const float*)d_in[7];
  const float* Wih   = (const float*)d_in[8];
  const float* Whh   = (const float*)d_in[9];
  const float* bih   = (const float*)d_in[10];
  const float* bhh   = (const float*)d_in[11];
  const int*   klen  = (const int*)d_in[12];

  char* ws = (char*)d_ws;
  unsigned short* att_bf = (unsigned short*)(ws + OFF_ATT);
  float*  c_ws  = (float*)(ws + OFF_C);
  float*  u1_ws = (float*)(ws + OFF_U1);
  short8* fr_ws = (short8*)(ws + OFF_FR);
  short8* w1f_ws = (short8*)(ws + OFF_W1F);
  float* out = (float*)d_out;

  hipLaunchKernelGGL(prep_kernel, dim3(1), dim3(256), 0, stream, W0, W1, u1_ws, fr_ws, w1f_ws);
  hipLaunchKernelGGL(c_kernel, dim3(B_N / 16), dim3(256), 0, stream, query, u1_ws, b0, c_ws);
  hipLaunchKernelGGL(att_kernel, dim3(4, B_N), dim3(256), 0, stream,
                     query, keys, c_ws, fr_ws, w1f_ws, b1, Wd, bd, klen, att_bf);
  hipLaunchKernelGGL(scan_kernel, dim3(B_N / 8), dim3(512), 0, stream,
                     keys, Wih, Whh, bih, bhh, klen, att_bf, out);
}

// Round 4
// 646.215 us; speedup vs baseline: 1.0319x; 1.0319x over previous
//
#include <hip/hip_runtime.h>
#include <stdint.h>
#include <stddef.h>

#define B_N   2048
#define T_SEQ 200
#define H_DIM 128

typedef __attribute__((ext_vector_type(8))) short short8;
typedef __attribute__((ext_vector_type(4))) float floatx4;

// ws layout (bytes) — total 1,411,072 <= 1,638,400 proven safe in R1
#define OFF_ATT 0u         // ushort[B][T]        819200
#define OFF_C   819200u    // float [B][64]       524288
#define OFF_U1  1343488u   // float [128][64]      32768
#define OFF_FR  1376256u   // short8[4][8][64]     32768
#define OFF_W1F 1409024u   // short8[2][64]         2048

__device__ __forceinline__ unsigned rnd_bf(float f) {
  union { float f; unsigned u; } v; v.f = f;
  return v.u + 0x7FFFu + ((v.u >> 16) & 1u);
}
__device__ __forceinline__ unsigned short f2bf(float f) {
  return (unsigned short)(rnd_bf(f) >> 16);
}
__device__ __forceinline__ unsigned pack2bf(float lo, float hi) {
  return __builtin_amdgcn_perm(rnd_bf(hi), rnd_bf(lo), 0x07060302u);
}
__device__ __forceinline__ float bf2f(unsigned short u) {
  union { unsigned u; float f; } v; v.u = ((unsigned)u) << 16; return v.f;
}
__device__ __forceinline__ float bf_lo(unsigned u) {
  union { unsigned u; float f; } v; v.u = u << 16; return v.f;
}
__device__ __forceinline__ float bf_hi(unsigned u) {
  union { unsigned u; float f; } v; v.u = u & 0xFFFF0000u; return v.f;
}

#define LOG2E 1.4426950408889634f
__device__ __forceinline__ float fsig(float x) {
  return 1.0f / (1.0f + __builtin_amdgcn_exp2f(-LOG2E * x));
}
__device__ __forceinline__ float ftanh(float x) {
  return fmaf(2.0f, 1.0f / (1.0f + __builtin_amdgcn_exp2f(-2.0f * LOG2E * x)), -1.0f);
}

__device__ __forceinline__ floatx4 mfma16(short8 a, short8 b, floatx4 c) {
  return __builtin_amdgcn_mfma_f32_16x16x32_bf16(a, b, c, 0, 0, 0);
}
__device__ __forceinline__ short8 pack8(const float* p) {
  short8 r;
#pragma unroll
  for (int j = 0; j < 8; ++j) r[j] = (short)f2bf(p[j]);
  return r;
}

// lgkm-only barrier: LDS ops drained, global loads (vmcnt) stay in flight
#define BARSYNC() __asm__ volatile("s_waitcnt lgkmcnt(0)\n\ts_barrier" ::: "memory")
#define WAVE_LDS_FENCE() __asm__ volatile("s_waitcnt lgkmcnt(0)" ::: "memory")

// ---------------------------------------------------------------------------
// prep (24 blocks): fold W0 -> u1 fp32 + bf16 MFMA B-frags for layer0/layer1
// ---------------------------------------------------------------------------
__global__ __launch_bounds__(256) void prep_kernel(
    const float* __restrict__ W0, const float* __restrict__ W1,
    float* __restrict__ u1_ws, short8* __restrict__ fr_ws,
    short8* __restrict__ w1f_ws)
{
  const int gid = blockIdx.x * 256 + threadIdx.x;
  const int gstride = gridDim.x * 256;
  for (int i = gid; i < 128 * 64; i += gstride) {
    int k = i >> 6, o = i & 63;
    u1_ws[i] = W0[o * 512 + k] + W0[o * 512 + 256 + k];
  }
  for (int f = gid; f < 4 * 8 * 64; f += gstride) {
    int ln = f & 63, kc = (f >> 6) & 7, tt = f >> 9;
    int o = tt * 16 + (ln & 15);
    int k0 = kc * 32 + ((ln >> 4) * 8);
    short8 v;
#pragma unroll
    for (int j = 0; j < 8; ++j) {
      int ks = k0 + j;
      float x = (ks < 128) ? (W0[o * 512 + 128 + ks] - W0[o * 512 + 256 + ks])
                           : W0[o * 512 + 384 + (ks - 128)];
      v[j] = (short)f2bf(x);
    }
    fr_ws[f] = v;
  }
  for (int f = gid; f < 2 * 64; f += gstride) {
    int ln = f & 63, kc = f >> 6;
    int n = ln & 15, k0 = kc * 32 + ((ln >> 4) * 8);
    short8 v;
#pragma unroll
    for (int j = 0; j < 8; ++j) v[j] = (short)f2bf(W1[n * 64 + k0 + j]);
    w1f_ws[f] = v;
  }
}

// ---------------------------------------------------------------------------
// c_kernel: c[b][o] = b0[o] + sum_k q[b][k] * u1[k][o].  16 b per block.
// ---------------------------------------------------------------------------
__global__ __launch_bounds__(256) void c_kernel(
    const float* __restrict__ query, const float* __restrict__ u1_ws,
    const float* __restrict__ b0, float* __restrict__ c_ws)
{
  const int blk = blockIdx.x, tid = threadIdx.x;
  __shared__ float qs[16 * 128];
  for (int i = tid; i < 512; i += 256)
    *(float4*)&qs[i * 4] = *(const float4*)(query + (size_t)blk * 2048 + i * 4);
  __syncthreads();
  const int o = tid & 63, bb = tid >> 6;
  float a0 = b0[o], a1 = a0, a2 = a0, a3 = a0;
  const float* qr = qs + bb * 512;
#pragma unroll 4
  for (int k = 0; k < 128; ++k) {
    float w = u1_ws[k * 64 + o];
    a0 = fmaf(qr[k], w, a0);
    a1 = fmaf(qr[128 + k], w, a1);
    a2 = fmaf(qr[256 + k], w, a2);
    a3 = fmaf(qr[384 + k], w, a3);
  }
  const int b = blk * 16 + bb * 4;
  c_ws[(b + 0) * 64 + o] = a0;
  c_ws[(b + 1) * 64 + o] = a1;
  c_ws[(b + 2) * 64 + o] = a2;
  c_ws[(b + 3) * 64 + o] = a3;
}

// ---------------------------------------------------------------------------
// att v4: 8 b's per block (B-frags in registers, reused), zero block barriers.
// grid (4 t-tiles, 256 b-groups) x 256 thr.
// ---------------------------------------------------------------------------
__global__ __launch_bounds__(256) void att_kernel(
    const float* __restrict__ query, const float* __restrict__ keys,
    const float* __restrict__ c_ws, const short8* __restrict__ fr_ws,
    const short8* __restrict__ w1f_ws, const float* __restrict__ b1,
    const float* __restrict__ Wd, const float* __restrict__ bd,
    const int* __restrict__ klen, unsigned short* __restrict__ attb)
{
  const int tt0 = blockIdx.x * 64;
  const int bg  = blockIdx.y * 8;
  const int tid = threadIdx.x;
  const int lane = tid & 63, wv = tid >> 6;
  const int l15 = lane & 15;
  const int kb = (lane >> 4) * 8;

  __shared__ unsigned short A[64][264];

  // hoisted B-fragments: 4 o-tiles x 8 k-chunks (loaded once, reused 8 b's)
  short8 bfr[4][8];
#pragma unroll
  for (int tt = 0; tt < 4; ++tt)
#pragma unroll
    for (int kc = 0; kc < 8; ++kc)
      bfr[tt][kc] = fr_ws[(size_t)tt * 512 + kc * 64 + lane];
  short8 w1f0 = w1f_ws[lane], w1f1 = w1f_ws[64 + lane];
  const float b1v = b1[l15];
  const float wd = Wd[l15];

  for (int bb = 0; bb < 8; ++bb) {
    const int b = bg + bb;
    const int len = klen[b];
    if (tt0 >= len) {
      if (tid < 64) {
        int tg = tt0 + tid;
        if (tg < T_SEQ) attb[(size_t)b * T_SEQ + tg] = 0;
      }
      continue;
    }

    {  // stage A = [k | q*k] bf16 — wave-local rows
      int tl = wv * 16 + (lane >> 2), q4 = lane & 3;
      int tg = tt0 + tl;
      bool v = (tg < T_SEQ);
      const float* krow = keys + ((size_t)b * T_SEQ + (v ? tg : 0)) * H_DIM + q4 * 32;
      const float* qrow = query + (size_t)b * H_DIM + q4 * 32;
#pragma unroll
      for (int i = 0; i < 32; i += 4) {
        float4 kv = v ? *(const float4*)(krow + i) : make_float4(0.f, 0.f, 0.f, 0.f);
        float4 qv = *(const float4*)(qrow + i);
        int col = q4 * 32 + i;
        *(unsigned*)&A[tl][col]           = pack2bf(kv.x, kv.y);
        *(unsigned*)&A[tl][col + 2]       = pack2bf(kv.z, kv.w);
        *(unsigned*)&A[tl][128 + col]     = pack2bf(kv.x * qv.x, kv.y * qv.y);
        *(unsigned*)&A[tl][128 + col + 2] = pack2bf(kv.z * qv.z, kv.w * qv.w);
      }
    }
    WAVE_LDS_FENCE();

    short8 af[8];
    {
      int arow = wv * 16 + l15;
#pragma unroll
      for (int kc = 0; kc < 8; ++kc) af[kc] = *(const short8*)&A[arow][kc * 32 + kb];
    }

    float a0v[4][4];
#pragma unroll
    for (int tt = 0; tt < 4; ++tt) {
      float co = c_ws[(size_t)b * 64 + tt * 16 + l15];
      floatx4 acc = {co, co, co, co};
#pragma unroll
      for (int kc = 0; kc < 8; ++kc) acc = mfma16(af[kc], bfr[tt][kc], acc);
#pragma unroll
      for (int r = 0; r < 4; ++r) a0v[tt][r] = fsig(acc[r]);
    }

    {  // wave-local transpose into own A rows
      int wrow = wv * 16 + (lane >> 4) * 4;
#pragma unroll
      for (int tt = 0; tt < 4; ++tt)
#pragma unroll
        for (int r = 0; r < 4; ++r)
          A[wrow + r][tt * 16 + l15] = f2bf(a0v[tt][r]);
    }
    WAVE_LDS_FENCE();

    floatx4 acc1 = {b1v, b1v, b1v, b1v};
    {
      int arow = wv * 16 + l15;
      acc1 = mfma16(*(const short8*)&A[arow][kb],      w1f0, acc1);
      acc1 = mfma16(*(const short8*)&A[arow][32 + kb], w1f1, acc1);
    }

    {
      float v0 = fsig(acc1[0]) * wd, v1 = fsig(acc1[1]) * wd;
      float v2 = fsig(acc1[2]) * wd, v3 = fsig(acc1[3]) * wd;
#pragma unroll
      for (int m = 1; m < 16; m <<= 1) {
        v0 += __shfl_xor(v0, m, 64);
        v1 += __shfl_xor(v1, m, 64);
        v2 += __shfl_xor(v2, m, 64);
        v3 += __shfl_xor(v3, m, 64);
      }
      if (l15 == 0) {
        float bdv = bd[0];
        int tbase = tt0 + wv * 16 + (lane >> 4) * 4;
        float vv[4] = {v0, v1, v2, v3};
#pragma unroll
        for (int r = 0; r < 4; ++r) {
          int tg = tbase + r;
          if (tg < T_SEQ)
            attb[(size_t)b * T_SEQ + tg] = (tg < len) ? f2bf(vv[r] + bdv) : (unsigned short)0;
        }
      }
    }
  }
}

// ---------------------------------------------------------------------------
// scan v4: producer/consumer wave specialization.
// 128 blocks x 16 rows x 1024 thr (16 waves). Waves 0-7: gh MFMA + gates.
// Waves 8-15: gi[t+1] MFMA into double-buffered LDS + k staging.
// One lgkm-only barrier per step.
// ---------------------------------------------------------------------------
__global__ __launch_bounds__(1024, 4) void scan_kernel(
    const float* __restrict__ keys, const float* __restrict__ Wih,
    const float* __restrict__ Whh, const float* __restrict__ bih,
    const float* __restrict__ bhh, const int* __restrict__ klen,
    const unsigned short* __restrict__ attb, float* __restrict__ out)
{
  const int r0 = blockIdx.x * 16;
  const int tid = threadIdx.x;
  const int lane = tid & 63, wv = tid >> 6;
  const int l15 = lane & 15, q = lane >> 4;
  const int kb = q * 8;

  __shared__ unsigned short hbf[2][16][136];
  __shared__ unsigned short kbf[2][16][136];
  __shared__ unsigned short gi_lds[2][3][128][16];  // [buf][sec][col][row]
  __shared__ unsigned short att_s[T_SEQ][16];
  __shared__ int len_s[16];

  if (tid < 16) len_s[tid] = klen[r0 + tid];

  if (tid < 512) {
    // consumers: zero hbf[0], stage att_s (bf16)
    for (int i = tid; i < 16 * 136 / 2; i += 512) ((unsigned*)hbf[0])[i] = 0;
    for (int i = tid; i < T_SEQ * 16; i += 512) {
      int t = i >> 4, m = i & 15;
      att_s[t][m] = attb[(size_t)(r0 + m) * T_SEQ + t];
    }
  } else {
    // producers: stage k0 -> kbf[0], k1 -> kbf[1]
    int ptid = tid - 512;
    int pm = ptid >> 5, pjf = (ptid & 31) * 4;
    const float* kbase = keys + ((size_t)(r0 + pm) * T_SEQ) * H_DIM + pjf;
    float4 k0 = *(const float4*)kbase;
    float4 k1 = *(const float4*)(kbase + H_DIM);
    uint2 p0; p0.x = pack2bf(k0.x, k0.y); p0.y = pack2bf(k0.z, k0.w);
    uint2 p1; p1.x = pack2bf(k1.x, k1.y); p1.y = pack2bf(k1.z, k1.w);
    *(uint2*)&kbf[0][pm][pjf] = p0;
    *(uint2*)&kbf[1][pm][pjf] = p1;
  }
  BARSYNC();  // #1

  int tmax = 0;
#pragma unroll
  for (int m = 0; m < 16; ++m) tmax = max(tmax, len_s[m]);

  if (tid < 512) {
    // ================= CONSUMER =================
    const int ocol = wv * 16 + l15;
    const int mrow0 = q * 4;
    short8 whf[3][4];
#pragma unroll
    for (int g = 0; g < 3; ++g) {
      int row = g * 128 + ocol;
#pragma unroll
      for (int kc = 0; kc < 4; ++kc)
        whf[g][kc] = pack8(Whh + (size_t)row * H_DIM + kc * 32 + kb);
    }
    const float br_  = bih[ocol] + bhh[ocol];
    const float bz_  = bih[128 + ocol] + bhh[128 + ocol];
    const float bin_ = bih[256 + ocol];
    const float bhn_ = bhh[256 + ocol];
    int lenr[4];
    float hreg[4];
#pragma unroll
    for (int r = 0; r < 4; ++r) { lenr[r] = len_s[mrow0 + r]; hreg[r] = 0.0f; }

    BARSYNC();  // #2 (gi[0] ready)

    for (int t = 0; t < tmax; ++t) {
      const int buf = t & 1, nbuf = buf ^ 1;
      short8 ah0 = *(const short8*)&hbf[buf][l15][kb];
      short8 ah1 = *(const short8*)&hbf[buf][l15][32 + kb];
      short8 ah2 = *(const short8*)&hbf[buf][l15][64 + kb];
      short8 ah3 = *(const short8*)&hbf[buf][l15][96 + kb];

      floatx4 ar = {br_, br_, br_, br_};
      floatx4 az = {bz_, bz_, bz_, bz_};
      floatx4 an = {bhn_, bhn_, bhn_, bhn_};
      ar = mfma16(ah0, whf[0][0], ar); az = mfma16(ah0, whf[1][0], az); an = mfma16(ah0, whf[2][0], an);
      ar = mfma16(ah1, whf[0][1], ar); az = mfma16(ah1, whf[1][1], az); an = mfma16(ah1, whf[2][1], an);
      ar = mfma16(ah2, whf[0][2], ar); az = mfma16(ah2, whf[1][2], az); an = mfma16(ah2, whf[2][2], an);
      ar = mfma16(ah3, whf[0][3], ar); az = mfma16(ah3, whf[1][3], az); an = mfma16(ah3, whf[2][3], an);

      uint2 g_r = *(const uint2*)&gi_lds[buf][0][ocol][mrow0];
      uint2 g_z = *(const uint2*)&gi_lds[buf][1][ocol][mrow0];
      uint2 g_n = *(const uint2*)&gi_lds[buf][2][ocol][mrow0];
      uint2 av  = *(const uint2*)&att_s[t][mrow0];
      float gir[4] = {bf_lo(g_r.x), bf_hi(g_r.x), bf_lo(g_r.y), bf_hi(g_r.y)};
      float giz[4] = {bf_lo(g_z.x), bf_hi(g_z.x), bf_lo(g_z.y), bf_hi(g_z.y)};
      float gin[4] = {bf_lo(g_n.x), bf_hi(g_n.x), bf_lo(g_n.y), bf_hi(g_n.y)};
      float atv[4] = {bf_lo(av.x),  bf_hi(av.x),  bf_lo(av.y),  bf_hi(av.y)};

#pragma unroll
      for (int r = 0; r < 4; ++r) {
        float rr = fsig(ar[r] + gir[r]);
        float zz = fsig(az[r] + giz[r]);
        float nn = ftanh(gin[r] + bin_ + rr * an[r]);
        float z2 = atv[r] * zz;
        float hn = fmaf(z2, nn - hreg[r], hreg[r]);
        hreg[r] = (t < lenr[r]) ? hn : hreg[r];
        hbf[nbuf][mrow0 + r][ocol] = f2bf(hreg[r]);
      }
      BARSYNC();
    }

#pragma unroll
    for (int r = 0; r < 4; ++r)
      out[(size_t)(r0 + mrow0 + r) * H_DIM + ocol] = hreg[r];

  } else {
    // ================= PRODUCER =================
    const int pw = wv - 8;
    const int ocp = pw * 16 + l15;
    const int ptid = tid - 512;
    const int pm = ptid >> 5, pjf = (ptid & 31) * 4;
    const float* kbase = keys + ((size_t)(r0 + pm) * T_SEQ) * H_DIM + pjf;

    float4 kv_next = *(const float4*)(kbase + 2 * H_DIM);  // k2

    short8 wif[3][4];
#pragma unroll
    for (int g = 0; g < 3; ++g) {
      int row = g * 128 + ocp;
#pragma unroll
      for (int kc = 0; kc < 4; ++kc)
        wif[g][kc] = pack8(Wih + (size_t)row * H_DIM + kc * 32 + kb);
    }

    // gi[0] from kbf[0]
    {
      short8 ak0 = *(const short8*)&kbf[0][l15][kb];
      short8 ak1 = *(const short8*)&kbf[0][l15][32 + kb];
      short8 ak2 = *(const short8*)&kbf[0][l15][64 + kb];
      short8 ak3 = *(const short8*)&kbf[0][l15][96 + kb];
      floatx4 a0 = {0.f,0.f,0.f,0.f}, a1 = {0.f,0.f,0.f,0.f}, a2 = {0.f,0.f,0.f,0.f};
      a0 = mfma16(ak0, wif[0][0], a0); a1 = mfma16(ak0, wif[1][0], a1); a2 = mfma16(ak0, wif[2][0], a2);
      a0 = mfma16(ak1, wif[0][1], a0); a1 = mfma16(ak1, wif[1][1], a1); a2 = mfma16(ak1, wif[2][1], a2);
      a0 = mfma16(ak2, wif[0][2], a0); a1 = mfma16(ak2, wif[1][2], a1); a2 = mfma16(ak2, wif[2][2], a2);
      a0 = mfma16(ak3, wif[0][3], a0); a1 = mfma16(ak3, wif[1][3], a1); a2 = mfma16(ak3, wif[2][3], a2);
      uint2 p;
      p.x = pack2bf(a0[0], a0[1]); p.y = pack2bf(a0[2], a0[3]);
      *(uint2*)&gi_lds[0][0][ocp][q * 4] = p;
      p.x = pack2bf(a1[0], a1[1]); p.y = pack2bf(a1[2], a1[3]);
      *(uint2*)&gi_lds[0][1][ocp][q * 4] = p;
      p.x = pack2bf(a2[0], a2[1]); p.y = pack2bf(a2[2], a2[3]);
      *(uint2*)&gi_lds[0][2][ocp][q * 4] = p;
    }
    BARSYNC();  // #2

    for (int t = 0; t < tmax; ++t) {
      const int buf = t & 1, nbuf = buf ^ 1;
      int tf = min(t + 3, T_SEQ - 1);
      float4 kv_fut = *(const float4*)(kbase + (size_t)tf * H_DIM);

      // gi[t+1] from kbf[nbuf]
      short8 ak0 = *(const short8*)&kbf[nbuf][l15][kb];
      short8 ak1 = *(const short8*)&kbf[nbuf][l15][32 + kb];
      short8 ak2 = *(const short8*)&kbf[nbuf][l15][64 + kb];
      short8 ak3 = *(const short8*)&kbf[nbuf][l15][96 + kb];
      floatx4 a0 = {0.f,0.f,0.f,0.f}, a1 = {0.f,0.f,0.f,0.f}, a2 = {0.f,0.f,0.f,0.f};
      a0 = mfma16(ak0, wif[0][0], a0); a1 = mfma16(ak0, wif[1][0], a1); a2 = mfma16(ak0, wif[2][0], a2);
      a0 = mfma16(ak1, wif[0][1], a0); a1 = mfma16(ak1, wif[1][1], a1); a2 = mfma16(ak1, wif[2][1], a2);
      a0 = mfma16(ak2, wif[0][2], a0); a1 = mfma16(ak2, wif[1][2], a1); a2 = mfma16(ak2, wif[2][2], a2);
      a0 = mfma16(ak3, wif[0][3], a0); a1 = mfma16(ak3, wif[1][3], a1); a2 = mfma16(ak3, wif[2][3], a2);
      uint2 p;
      p.x = pack2bf(a0[0], a0[1]); p.y = pack2bf(a0[2], a0[3]);
      *(uint2*)&gi_lds[nbuf][0][ocp][q * 4] = p;
      p.x = pack2bf(a1[0], a1[1]); p.y = pack2bf(a1[2], a1[3]);
      *(uint2*)&gi_lds[nbuf][1][ocp][q * 4] = p;
      p.x = pack2bf(a2[0], a2[1]); p.y = pack2bf(a2[2], a2[3]);
      *(uint2*)&gi_lds[nbuf][2][ocp][q * 4] = p;

      // stage k[t+2] into kbf[buf] (consumed two iterations from now)
      uint2 pk; pk.x = pack2bf(kv_next.x, kv_next.y); pk.y = pack2bf(kv_next.z, kv_next.w);
      *(uint2*)&kbf[buf][pm][pjf] = pk;
      kv_next = kv_fut;
      BARSYNC();
    }
  }
}

extern "C" void kernel_launch(void* const* d_in, const int* in_sizes, int n_in,
                              void* d_out, int out_size, void* d_ws, size_t ws_size,
                              hipStream_t stream) {
  const float* query = (const float*)d_in[0];
  const float* keys  = (const float*)d_in[1];
  const float* W0    = (const float*)d_in[2];
  const float* b0    = (const float*)d_in[3];
  const float* W1    = (const float*)d_in[4];
  const float* b1    = (const float*)d_in[5];
  const float* Wd    = (const float*)d_in[6];
  const float* bd    = (const float*)d_in[7];
  const float* Wih   = (const float*)d_in[8];
  const float* Whh   = (const float*)d_in[9];
  const float* bih   = (const float*)d_in[10];
  const float* bhh   = (const float*)d_in[11];
  const int*   klen  = (const int*)d_in[12];

  char* ws = (char*)d_ws;
  unsigned short* att_bf = (unsigned short*)(ws + OFF_ATT);
  float*  c_ws  = (float*)(ws + OFF_C);
  float*  u1_ws = (float*)(ws + OFF_U1);
  short8* fr_ws = (short8*)(ws + OFF_FR);
  short8* w1f_ws = (short8*)(ws + OFF_W1F);
  float* out = (float*)d_out;

  hipLaunchKernelGGL(prep_kernel, dim3(24), dim3(256), 0, stream, W0, W1, u1_ws, fr_ws, w1f_ws);
  hipLaunchKernelGGL(c_kernel, dim3(B_N / 16), dim3(256), 0, stream, query, u1_ws, b0, c_ws);
  hipLaunchKernelGGL(att_kernel, dim3(4, B_N / 8), dim3(256), 0, stream,
                     query, keys, c_ws, fr_ws, w1f_ws, b1, Wd, bd, klen, att_bf);
  hipLaunchKernelGGL(scan_kernel, dim3(B_N / 16), dim3(1024), 0, stream,
                     keys, Wih, Whh, bih, bhh, klen, att_bf, out);
}